// Round 10
// baseline (190.099 us; speedup 1.0000x reference)
//
#include <hip/hip_runtime.h>
#include <hip/hip_bf16.h>
#include <math.h>

// Problem constants
#define Bb 4
#define Tt 1024
#define Cc 1024
#define Hh 16
#define Dd 64

typedef __attribute__((ext_vector_type(8))) _Float16 half8;
typedef __attribute__((ext_vector_type(4))) _Float16 half4;
typedef __attribute__((ext_vector_type(4))) float floatx4;

// Fragment-swizzled layout for an [R x 1024] f16 matrix:
//   addr(row,k) = (row>>4)*16384 + (k>>3)*128 + (row&15)*8 + (k&7)
// A wave's 16x16x32-MFMA operand fragment (rows 16-aligned, k 32-aligned) is
// base + lane*8 elems -> one coalesced global_load_dwordx4, and each fragment
// is 1024 B CONTIGUOUS -> global_load_lds stages it as a linear copy.

__device__ __forceinline__ void gload_lds16(const _Float16* g, const _Float16* l)
{
    __builtin_amdgcn_global_load_lds(
        (const __attribute__((address_space(1))) void*)g,
        (__attribute__((address_space(3))) void*)l, 16, 0, 0);
}

// ---------------------------------------------------------------------------
// prep_all: merged convert + weight-prep (one dispatch; verified). UNCHANGED.
// ---------------------------------------------------------------------------
struct PrepP { const float* x; _Float16* xh; const float* W[4]; _Float16* out[4]; };

__global__ __launch_bounds__(256) void prep_all(PrepP p)
{
    if (blockIdx.x < 256) {
        const int m16 = blockIdx.x;
        const int r   = threadIdx.x & 15;
        const int kc0 = threadIdx.x >> 4;
        const float* src = p.x + (size_t)(m16 * 16 + r) * 1024;
        _Float16*   dst = p.xh + (size_t)m16 * 16384 + r * 8;
#pragma unroll
        for (int c8 = 0; c8 < 8; ++c8) {
            const int kc = kc0 + c8 * 16;
            float4 a = *(const float4*)(src + kc * 8);
            float4 b = *(const float4*)(src + kc * 8 + 4);
            half8 h;
            h[0] = (_Float16)a.x; h[1] = (_Float16)a.y; h[2] = (_Float16)a.z; h[3] = (_Float16)a.w;
            h[4] = (_Float16)b.x; h[5] = (_Float16)b.y; h[6] = (_Float16)b.z; h[7] = (_Float16)b.w;
            *(half8*)(dst + kc * 128) = h;
        }
        return;
    }
    const int bid2 = blockIdx.x - 256;
    const int z    = bid2 >> 8;
    const int rem  = bid2 & 255;
    const int n0   = (rem & 15) * 64;
    const int k0   = (rem >> 4) * 64;
    const float* __restrict__ W = p.W[z];
    _Float16* __restrict__ outp = p.out[z];
    __shared__ float tile[64][65];
    const int tr  = threadIdx.x >> 4;
    const int tc4 = (threadIdx.x & 15) * 4;

#pragma unroll
    for (int i = 0; i < 4; ++i) {
        const int kk = tr + i * 16;
        float4 v = *(const float4*)(W + (size_t)(k0 + kk) * 1024 + n0 + tc4);
        tile[kk][tc4 + 0] = v.x;
        tile[kk][tc4 + 1] = v.y;
        tile[kk][tc4 + 2] = v.z;
        tile[kk][tc4 + 3] = v.w;
    }
    __syncthreads();
#pragma unroll
    for (int i = 0; i < 4; ++i) {
        half4 h;
#pragma unroll
        for (int c = 0; c < 4; ++c) h[c] = (_Float16)tile[tc4 + c][tr + i * 16];
        _Float16* dst = outp + (size_t)((n0 >> 4) + i) * 16384
                        + ((k0 + tc4) >> 3) * 128 + tr * 8 + (tc4 & 7);
        *(half4*)dst = h;
    }
}

// ---------------------------------------------------------------------------
// gemm_qkv: ROUND-6 (verified win) — 8-wave 128^2 block, T3+T4 counted-vmcnt
// 3-buffer pipeline. 24 waves/CU. UNCHANGED.
// ---------------------------------------------------------------------------
struct QkvP { const _Float16* Wt[3]; const float* bias[3];
              _Float16* qb; _Float16* kb; _Float16* vt; };

#define QKV_STEP(CUR, SBUF, TS, DOSTAGE, TAILWAIT)                          \
    {                                                                       \
        half8 af[2], bf[4];                                                 \
        _Pragma("unroll")                                                   \
        for (int i = 0; i < 2; ++i)                                         \
            af[i] = *(const half8*)&As[CUR][wr * 2 + i][lane * 8];          \
        _Pragma("unroll")                                                   \
        for (int j = 0; j < 4; ++j)                                         \
            bf[j] = *(const half8*)&Bs[CUR][wc * 4 + j][lane * 8];          \
        if (DOSTAGE) {                                                      \
            const size_t ko = (size_t)(TS) * 512;                           \
            gload_lds16(ga + ko, &As[SBUF][w][0]);                          \
            gload_lds16(gb + ko, &Bs[SBUF][w][0]);                          \
        }                                                                   \
        _Pragma("unroll")                                                   \
        for (int i = 0; i < 2; ++i)                                         \
            _Pragma("unroll")                                               \
            for (int j = 0; j < 4; ++j)                                     \
                acc[i][j] = __builtin_amdgcn_mfma_f32_16x16x32_f16(         \
                    af[i], bf[j], acc[i][j], 0, 0, 0);                      \
        if ((TAILWAIT) == 2)                                                \
            asm volatile("s_waitcnt vmcnt(2)" ::: "memory");                \
        else if ((TAILWAIT) == 0)                                           \
            asm volatile("s_waitcnt vmcnt(0)" ::: "memory");                \
        if ((TAILWAIT) >= 0) __builtin_amdgcn_s_barrier();                  \
    }

__global__ __launch_bounds__(512) void gemm_qkv(const _Float16* __restrict__ xh, QkvP p)
{
    const int z = blockIdx.z;
    const _Float16* __restrict__ Wt   = p.Wt[z];
    const float* __restrict__    bias = p.bias[z];

    const int tid  = threadIdx.x;
    const int lane = tid & 63;
    const int w    = tid >> 6;        // 8 waves
    const int wr   = w >> 1, wc = w & 1;   // 4M x 2N wave grid
    const int quad = lane >> 4;
    const int l15  = lane & 15;
    const int bm   = blockIdx.x * 128;
    const int bn   = blockIdx.y * 128;

    __shared__ __align__(16) _Float16 As[3][8][512];
    __shared__ __align__(16) _Float16 Bs[3][8][512];

    const _Float16* ga = xh + (size_t)((bm >> 4) + w) * 16384 + lane * 8;
    const _Float16* gb = Wt + (size_t)((bn >> 4) + w) * 16384 + lane * 8;

    floatx4 acc[2][4];
#pragma unroll
    for (int i = 0; i < 2; ++i)
#pragma unroll
        for (int j = 0; j < 4; ++j)
            acc[i][j] = (floatx4){0.f, 0.f, 0.f, 0.f};

    gload_lds16(ga, &As[0][w][0]);
    gload_lds16(gb, &Bs[0][w][0]);
    gload_lds16(ga + 512, &As[1][w][0]);
    gload_lds16(gb + 512, &Bs[1][w][0]);
    asm volatile("s_waitcnt vmcnt(2)" ::: "memory");  // tile 0 landed
    __builtin_amdgcn_s_barrier();

    for (int tt = 0; tt < 30; tt += 3) {
        QKV_STEP(0, 2, tt + 2, true, 2);
        QKV_STEP(1, 0, tt + 3, true, 2);
        QKV_STEP(2, 1, tt + 4, true, 2);
    }
    QKV_STEP(0, 0, 0, false, 0);   // t=30: drain tile 31
    QKV_STEP(1, 0, 0, false, -1);  // t=31: no wait, no barrier

    if (z == 2) {
#pragma unroll
        for (int j = 0; j < 4; ++j) {
            const int col = bn + wc * 64 + j * 16 + l15;
            const int h  = col >> 6;
            const float bj = bias[col];
#pragma unroll
            for (int i = 0; i < 2; ++i) {
                const int t0 = bm + wr * 32 + i * 16 + quad * 4;
                const int bh = (t0 >> 10) * 16 + h;
                const int tm = t0 & 1023;
                half4 pk;
#pragma unroll
                for (int r = 0; r < 4; ++r) pk[r] = (_Float16)(acc[i][j][r] + bj);
                *(half4*)(p.vt + (size_t)bh * 65536 + (size_t)j * 16384
                          + (tm >> 3) * 128 + l15 * 8 + (tm & 7)) = pk;
            }
        }
    } else {
        _Float16* outp = (z == 0) ? p.qb : p.kb;
#pragma unroll
        for (int j = 0; j < 4; ++j) {
            const int col = bn + wc * 64 + j * 16 + l15;
            const int h  = col >> 6;
            const int dd = col & 63;
            const float bj = bias[col];
            const int doff = (dd >> 3) * 128 + (dd & 7);
#pragma unroll
            for (int i = 0; i < 2; ++i) {
#pragma unroll
                for (int r = 0; r < 4; ++r) {
                    const int tg = bm + wr * 32 + i * 16 + quad * 4 + r;
                    const int bh = (tg >> 10) * 16 + h;
                    const int tm = tg & 1023;
                    outp[(size_t)bh * 65536 + (tm >> 4) * 1024 + doff + (tm & 15) * 8] =
                        (_Float16)(acc[i][j][r] + bj);
                }
            }
        }
    }
}

// ---------------------------------------------------------------------------
// attn_mfma: ROUND-9 — REVERT to the barrier-free r10 structure (r8's LDS
// staging + per-iter barrier REGRESSED: 53 us vs ~51; barrier lockstep on a
// long VALU-chain body costs more than the 4x L2 dedup saves) + T14 reg
// prefetch: ping-pong register sets ak0/bv0, ak1/bv1; tile t+1's 16 K/V
// loads issue BEFORE tile t's compute, landing under ~600 cyc of QK/softmax/
// PV. Static names via 2x-unrolled macro (no runtime-indexed vec arrays).
// VGPR +64 is free: occupancy is grid-limited at 2 blocks/CU.
// ---------------------------------------------------------------------------
#define ATTN_TILE(AKC, BVC, AKN, BVN, KTC, KTN, DOLOAD)                     \
    {                                                                       \
        if (DOLOAD) {                                                       \
            _Pragma("unroll")                                               \
            for (int ks = 0; ks < 2; ++ks) {                                \
                _Pragma("unroll")                                           \
                for (int mk = 0; mk < 4; ++mk)                              \
                    AKN[ks][mk] = *(const half8*)(kf                        \
                        + (size_t)(((KTN) >> 4) + mk) * 1024                \
                        + ks * 512 + lane * 8);                             \
                _Pragma("unroll")                                           \
                for (int dj = 0; dj < 4; ++dj)                              \
                    BVN[ks][dj] = *(const half8*)(vf + (size_t)dj * 16384   \
                        + ((KTN) >> 3) * 128 + ks * 512 + lane * 8);        \
            }                                                               \
        }                                                                   \
        float4 kk4[4];                                                      \
        _Pragma("unroll")                                                   \
        for (int mk = 0; mk < 4; ++mk)                                      \
            kk4[mk] = *(const float4*)(pk_row + (KTC) + mk * 16 + quad * 4);\
        floatx4 ST[4][2];                                                   \
        _Pragma("unroll")                                                   \
        for (int mk = 0; mk < 4; ++mk)                                      \
            _Pragma("unroll")                                               \
            for (int nq = 0; nq < 2; ++nq)                                  \
                ST[mk][nq] = (floatx4){0.f, 0.f, 0.f, 0.f};                 \
        _Pragma("unroll")                                                   \
        for (int ks = 0; ks < 2; ++ks)                                      \
            _Pragma("unroll")                                               \
            for (int mk = 0; mk < 4; ++mk)                                  \
                _Pragma("unroll")                                           \
                for (int nq = 0; nq < 2; ++nq)                              \
                    ST[mk][nq] = __builtin_amdgcn_mfma_f32_16x16x32_f16(    \
                        AKC[ks][mk], bq[ks][nq], ST[mk][nq], 0, 0, 0);      \
        _Pragma("unroll")                                                   \
        for (int mk = 0; mk < 4; ++mk) {                                    \
            const float kkr[4] = {1.0f - kk4[mk].x, 1.0f - kk4[mk].y,       \
                                  1.0f - kk4[mk].z, 1.0f - kk4[mk].w};      \
            _Pragma("unroll")                                               \
            for (int nq = 0; nq < 2; ++nq) {                                \
                half4 pk;                                                   \
                _Pragma("unroll")                                           \
                for (int r = 0; r < 4; ++r) {                               \
                    const float e = __builtin_amdgcn_exp2f(ST[mk][nq][r] * SC); \
                    const float pv = (kq[nq] == 0.0f) ? 1.0f : kkr[r] * e;  \
                    pk[r] = (_Float16)pv;                                   \
                }                                                           \
                *(half4*)&Ps[w][((mk * 2 + (quad >> 1)) * 32 + nq * 16 + l15) * 8 \
                               + (quad & 1) * 4] = pk;                      \
            }                                                               \
        }                                                                   \
        _Pragma("unroll")                                                   \
        for (int ks = 0; ks < 2; ++ks) {                                    \
            half8 ap[2];                                                    \
            _Pragma("unroll")                                               \
            for (int mi = 0; mi < 2; ++mi)                                  \
                ap[mi] = *(const half8*)&Ps[w][((ks * 4 + quad) * 32 + mi * 16 + l15) * 8]; \
            _Pragma("unroll")                                               \
            for (int mi = 0; mi < 2; ++mi) {                                \
                _Pragma("unroll")                                           \
                for (int dj = 0; dj < 4; ++dj)                              \
                    O[mi][dj] = __builtin_amdgcn_mfma_f32_16x16x32_f16(     \
                        ap[mi], BVC[ks][dj], O[mi][dj], 0, 0, 0);           \
                l_acc[mi] = __builtin_amdgcn_mfma_f32_16x16x32_f16(         \
                    ap[mi], ones, l_acc[mi], 0, 0, 0);                      \
            }                                                               \
        }                                                                   \
    }

__global__ __launch_bounds__(256) void attn_mfma(
    const _Float16* __restrict__ qb, const _Float16* __restrict__ kb,
    const _Float16* __restrict__ vt, const float* __restrict__ padj,
    _Float16* __restrict__ yh)
{
    __shared__ __align__(16) _Float16 Ps[4][2048];  // wave-private P

    const int tid  = threadIdx.x;
    const int lane = tid & 63;
    const int w    = tid >> 6;
    const int quad = lane >> 4;
    const int l15  = lane & 15;
    const int bh   = blockIdx.x;
    const int q0   = blockIdx.y * 128;
    const int b    = bh >> 4;
    const int h    = bh & 15;

    const _Float16* qf = qb + (size_t)bh * 65536;
    const _Float16* kf = kb + (size_t)bh * 65536;
    const _Float16* vf = vt + (size_t)bh * 65536;
    const float*    pk_row = padj + b * Tt;

    // Q frags: register-resident for entire K-loop (B-operand of S^T)
    half8 bq[2][2];
#pragma unroll
    for (int ks = 0; ks < 2; ++ks)
#pragma unroll
        for (int nq = 0; nq < 2; ++nq)
            bq[ks][nq] = *(const half8*)(qf + (size_t)((q0 >> 4) + w * 2 + nq) * 1024
                                         + ks * 512 + lane * 8);
    float kq[2];
#pragma unroll
    for (int nq = 0; nq < 2; ++nq)
        kq[nq] = 1.0f - pk_row[q0 + w * 32 + nq * 16 + l15];

    floatx4 O[2][4];
    floatx4 l_acc[2];
#pragma unroll
    for (int mi = 0; mi < 2; ++mi) {
#pragma unroll
        for (int dj = 0; dj < 4; ++dj) O[mi][dj] = (floatx4){0.f, 0.f, 0.f, 0.f};
        l_acc[mi] = (floatx4){0.f, 0.f, 0.f, 0.f};
    }
    half8 ones;
#pragma unroll
    for (int j = 0; j < 8; ++j) ones[j] = (_Float16)1.0f;

    constexpr float SC = 0.18033688011112042f;  // 0.125 * log2(e)

    // T14 prologue: tile 0 -> register set 0
    half8 ak0[2][4], bv0[2][4], ak1[2][4], bv1[2][4];
#pragma unroll
    for (int ks = 0; ks < 2; ++ks) {
#pragma unroll
        for (int mk = 0; mk < 4; ++mk)
            ak0[ks][mk] = *(const half8*)(kf + (size_t)mk * 1024 + ks * 512 + lane * 8);
#pragma unroll
        for (int dj = 0; dj < 4; ++dj)
            bv0[ks][dj] = *(const half8*)(vf + (size_t)dj * 16384 + ks * 512 + lane * 8);
    }

    // 16 K/V tiles, 2x-unrolled ping-pong: load(t+1) issued before compute(t)
    for (int tt = 0; tt < 896; tt += 128) {
        ATTN_TILE(ak0, bv0, ak1, bv1, tt, tt + 64, true);
        ATTN_TILE(ak1, bv1, ak0, bv0, tt + 64, tt + 128, true);
    }
    ATTN_TILE(ak0, bv0, ak1, bv1, 896, 960, true);
    ATTN_TILE(ak1, bv1, ak0, bv0, 960, 0, false);

    // epilogue: normalize, write yh frag-swizzled (for LDS-free proj)
#pragma unroll
    for (int mi = 0; mi < 2; ++mi) {
#pragma unroll
        for (int r = 0; r < 4; ++r) {
            const int rowl  = w * 32 + mi * 16 + quad * 4 + r;
            const int token = b * Tt + q0 + rowl;
            const float inv = 1.0f / l_acc[mi][r];
            const size_t tb = (size_t)(token >> 4) * 16384 + (token & 15) * 8;
#pragma unroll
            for (int dj = 0; dj < 4; ++dj) {
                const int col = h * 64 + dj * 16 + l15;
                yh[tb + (col >> 3) * 128 + (col & 7)] = (_Float16)(O[mi][dj][r] * inv);
            }
        }
    }
}

// ---------------------------------------------------------------------------
// gemm_proj: ROUND-7 8-wave counted-vmcnt 5-buffer pipeline. UNCHANGED.
// ---------------------------------------------------------------------------
#define PROJ_STEP(CUR, SBUF, TS, DOSTAGE, TAILWAIT)                         \
    {                                                                       \
        half8 af[2], bf[4];                                                 \
        _Pragma("unroll")                                                   \
        for (int i = 0; i < 2; ++i)                                         \
            af[i] = *(const half8*)&As[CUR][wr * 2 + i][lane * 8];          \
        _Pragma("unroll")                                                   \
        for (int j = 0; j < 4; ++j)                                         \
            bf[j] = *(const half8*)&Bs[CUR][wc * 4 + j][lane * 8];          \
        if (DOSTAGE) {                                                      \
            const size_t ko = (size_t)(TS) * 512;                           \
            gload_lds16(ga + ko, &As[SBUF][w][0]);                          \
            gload_lds16(gb + ko, &Bs[SBUF][w][0]);                          \
        }                                                                   \
        _Pragma("unroll")                                                   \
        for (int i = 0; i < 2; ++i)                                         \
            _Pragma("unroll")                                               \
            for (int j = 0; j < 4; ++j)                                     \
                acc[i][j] = __builtin_amdgcn_mfma_f32_16x16x32_f16(         \
                    af[i], bf[j], acc[i][j], 0, 0, 0);                      \
        if ((TAILWAIT) == 6)                                                \
            asm volatile("s_waitcnt vmcnt(6)" ::: "memory");                \
        else if ((TAILWAIT) == 4)                                           \
            asm volatile("s_waitcnt vmcnt(4)" ::: "memory");                \
        else if ((TAILWAIT) == 2)                                           \
            asm volatile("s_waitcnt vmcnt(2)" ::: "memory");                \
        else if ((TAILWAIT) == 0)                                           \
            asm volatile("s_waitcnt vmcnt(0)" ::: "memory");                \
        if ((TAILWAIT) >= 0) __builtin_amdgcn_s_barrier();                  \
    }

__global__ __launch_bounds__(512) void gemm_proj(const _Float16* __restrict__ Ay,
                                                 const _Float16* __restrict__ Bt,
                                                 const float* __restrict__ bias,
                                                 float* __restrict__ out)
{
    const int tid  = threadIdx.x;
    const int lane = tid & 63;
    const int w    = tid >> 6;             // 8 waves
    const int wr   = w >> 1, wc = w & 1;   // 4M x 2N wave grid
    const int quad = lane >> 4;
    const int l15  = lane & 15;
    const int bm   = blockIdx.x * 128;
    const int bn   = blockIdx.y * 128;

    __shared__ __align__(16) _Float16 As[5][8][512];
    __shared__ __align__(16) _Float16 Bs[5][8][512];

    const _Float16* ga = Ay + (size_t)((bm >> 4) + w) * 16384 + lane * 8;
    const _Float16* gb = Bt + (size_t)((bn >> 4) + w) * 16384 + lane * 8;

    floatx4 acc[2][4];
#pragma unroll
    for (int i = 0; i < 2; ++i)
#pragma unroll
        for (int j = 0; j < 4; ++j)
            acc[i][j] = (floatx4){0.f, 0.f, 0.f, 0.f};

#pragma unroll
    for (int tb = 0; tb < 4; ++tb) {
        gload_lds16(ga + (size_t)tb * 512, &As[tb][w][0]);
        gload_lds16(gb + (size_t)tb * 512, &Bs[tb][w][0]);
    }
    asm volatile("s_waitcnt vmcnt(6)" ::: "memory");  // tile 0 landed
    __builtin_amdgcn_s_barrier();

    for (int tt = 0; tt < 25; tt += 5) {
        PROJ_STEP(0, 4, tt + 4, true, 6);
        PROJ_STEP(1, 0, tt + 5, true, 6);
        PROJ_STEP(2, 1, tt + 6, true, 6);
        PROJ_STEP(3, 2, tt + 7, true, 6);
        PROJ_STEP(4, 3, tt + 8, true, 6);
    }
    PROJ_STEP(0, 4, 29, true, 6);   // t=25
    PROJ_STEP(1, 0, 30, true, 6);   // t=26
    PROJ_STEP(2, 1, 31, true, 6);   // t=27
    PROJ_STEP(3, 0, 0, false, 4);   // t=28
    PROJ_STEP(4, 0, 0, false, 2);   // t=29
    PROJ_STEP(0, 0, 0, false, 0);   // t=30
    PROJ_STEP(1, 0, 0, false, -1);  // t=31

#pragma unroll
    for (int j = 0; j < 4; ++j) {
        const int col = bn + wc * 64 + j * 16 + l15;
        const float bj = bias[col];
#pragma unroll
        for (int i = 0; i < 2; ++i) {
            const int row = bm + wr * 32 + i * 16 + quad * 4;
            float* o = out + (size_t)row * 1024 + col;
#pragma unroll
            for (int r = 0; r < 4; ++r)
                o[(size_t)r * 1024] = acc[i][j][r] + bj;
        }
    }
}

// ---------------------------------------------------------------------------
extern "C" void kernel_launch(void* const* d_in, const int* in_sizes, int n_in,
                              void* d_out, int out_size, void* d_ws, size_t ws_size,
                              hipStream_t stream)
{
    const float* x    = (const float*)d_in[0];
    const float* padj = (const float*)d_in[1];
    const float* Wq   = (const float*)d_in[2];
    const float* bq   = (const float*)d_in[3];
    const float* Wk   = (const float*)d_in[4];
    const float* bk   = (const float*)d_in[5];
    const float* Wv   = (const float*)d_in[6];
    const float* bv   = (const float*)d_in[7];
    const float* Wp   = (const float*)d_in[8];
    const float* bp   = (const float*)d_in[9];
    float* out = (float*)d_out;

    const size_t MB = 1024 * 1024;
    char* ws = (char*)d_ws;
    _Float16* xh  = (_Float16*)(ws);            //  8 MB (frag-swizzled)
    _Float16* Wt0 = (_Float16*)(ws +  8 * MB);  //  2 MB
    _Float16* Wt1 = (_Float16*)(ws + 10 * MB);  //  2 MB
    _Float16* Wt2 = (_Float16*)(ws + 12 * MB);  //  2 MB
    _Float16* Wtp = (_Float16*)(ws + 14 * MB);  //  2 MB
    _Float16* qb  = (_Float16*)(ws + 16 * MB);  //  8 MB (per-bh frag)
    _Float16* kb  = (_Float16*)(ws + 24 * MB);  //  8 MB (per-bh frag)
    _Float16* vtb = (_Float16*)(ws + 32 * MB);  //  8 MB (per-bh frag)
    _Float16* yh  = (_Float16*)(ws + 40 * MB);  //  8 MB (frag-swizzled) -> 48 MB

    PrepP pp;
    pp.x = x; pp.xh = xh;
    pp.W[0] = Wq; pp.W[1] = Wk; pp.W[2] = Wv; pp.W[3] = Wp;
    pp.out[0] = Wt0; pp.out[1] = Wt1; pp.out[2] = Wt2; pp.out[3] = Wtp;
    prep_all<<<1280, 256, 0, stream>>>(pp);

    QkvP qp;
    qp.Wt[0] = Wt0; qp.Wt[1] = Wt1; qp.Wt[2] = Wt2;
    qp.bias[0] = bq; qp.bias[1] = bk; qp.bias[2] = bv;
    qp.qb = qb; qp.kb = kb; qp.vt = vtb;
    gemm_qkv<<<dim3(32, 8, 3), 512, 0, stream>>>(xh, qp);

    attn_mfma<<<dim3(64, 8), 256, 0, stream>>>(qb, kb, vtb, padj, yh);

    gemm_proj<<<dim3(32, 8), 512, 0, stream>>>(yh, Wtp, bp, out);
}

// Round 11
// 168.469 us; speedup vs baseline: 1.1284x; 1.1284x over previous
//
#include <hip/hip_runtime.h>
#include <hip/hip_bf16.h>
#include <math.h>

// Problem constants
#define Bb 4
#define Tt 1024
#define Cc 1024
#define Hh 16
#define Dd 64

typedef __attribute__((ext_vector_type(8))) _Float16 half8;
typedef __attribute__((ext_vector_type(4))) _Float16 half4;
typedef __attribute__((ext_vector_type(4))) float floatx4;

// Fragment-swizzled layout for an [R x 1024] f16 matrix:
//   addr(row,k) = (row>>4)*16384 + (k>>3)*128 + (row&15)*8 + (k&7)
// A wave's 16x16x32-MFMA operand fragment (rows 16-aligned, k 32-aligned) is
// base + lane*8 elems -> one coalesced global_load_dwordx4, and each fragment
// is 1024 B CONTIGUOUS -> global_load_lds stages it as a linear copy.

__device__ __forceinline__ void gload_lds16(const _Float16* g, const _Float16* l)
{
    __builtin_amdgcn_global_load_lds(
        (const __attribute__((address_space(1))) void*)g,
        (__attribute__((address_space(3))) void*)l, 16, 0, 0);
}

// ---------------------------------------------------------------------------
// prep_all: merged convert + weight-prep (one dispatch; verified). UNCHANGED.
// ---------------------------------------------------------------------------
struct PrepP { const float* x; _Float16* xh; const float* W[4]; _Float16* out[4]; };

__global__ __launch_bounds__(256) void prep_all(PrepP p)
{
    if (blockIdx.x < 256) {
        const int m16 = blockIdx.x;
        const int r   = threadIdx.x & 15;
        const int kc0 = threadIdx.x >> 4;
        const float* src = p.x + (size_t)(m16 * 16 + r) * 1024;
        _Float16*   dst = p.xh + (size_t)m16 * 16384 + r * 8;
#pragma unroll
        for (int c8 = 0; c8 < 8; ++c8) {
            const int kc = kc0 + c8 * 16;
            float4 a = *(const float4*)(src + kc * 8);
            float4 b = *(const float4*)(src + kc * 8 + 4);
            half8 h;
            h[0] = (_Float16)a.x; h[1] = (_Float16)a.y; h[2] = (_Float16)a.z; h[3] = (_Float16)a.w;
            h[4] = (_Float16)b.x; h[5] = (_Float16)b.y; h[6] = (_Float16)b.z; h[7] = (_Float16)b.w;
            *(half8*)(dst + kc * 128) = h;
        }
        return;
    }
    const int bid2 = blockIdx.x - 256;
    const int z    = bid2 >> 8;
    const int rem  = bid2 & 255;
    const int n0   = (rem & 15) * 64;
    const int k0   = (rem >> 4) * 64;
    const float* __restrict__ W = p.W[z];
    _Float16* __restrict__ outp = p.out[z];
    __shared__ float tile[64][65];
    const int tr  = threadIdx.x >> 4;
    const int tc4 = (threadIdx.x & 15) * 4;

#pragma unroll
    for (int i = 0; i < 4; ++i) {
        const int kk = tr + i * 16;
        float4 v = *(const float4*)(W + (size_t)(k0 + kk) * 1024 + n0 + tc4);
        tile[kk][tc4 + 0] = v.x;
        tile[kk][tc4 + 1] = v.y;
        tile[kk][tc4 + 2] = v.z;
        tile[kk][tc4 + 3] = v.w;
    }
    __syncthreads();
#pragma unroll
    for (int i = 0; i < 4; ++i) {
        half4 h;
#pragma unroll
        for (int c = 0; c < 4; ++c) h[c] = (_Float16)tile[tc4 + c][tr + i * 16];
        _Float16* dst = outp + (size_t)((n0 >> 4) + i) * 16384
                        + ((k0 + tc4) >> 3) * 128 + tr * 8 + (tc4 & 7);
        *(half4*)dst = h;
    }
}

// ---------------------------------------------------------------------------
// gemm_qkv: ROUND-6 (verified win) — 8-wave 128^2 block, T3+T4 counted-vmcnt
// 3-buffer pipeline. 24 waves/CU. UNCHANGED.
// ---------------------------------------------------------------------------
struct QkvP { const _Float16* Wt[3]; const float* bias[3];
              _Float16* qb; _Float16* kb; _Float16* vt; };

#define QKV_STEP(CUR, SBUF, TS, DOSTAGE, TAILWAIT)                          \
    {                                                                       \
        half8 af[2], bf[4];                                                 \
        _Pragma("unroll")                                                   \
        for (int i = 0; i < 2; ++i)                                         \
            af[i] = *(const half8*)&As[CUR][wr * 2 + i][lane * 8];          \
        _Pragma("unroll")                                                   \
        for (int j = 0; j < 4; ++j)                                         \
            bf[j] = *(const half8*)&Bs[CUR][wc * 4 + j][lane * 8];          \
        if (DOSTAGE) {                                                      \
            const size_t ko = (size_t)(TS) * 512;                           \
            gload_lds16(ga + ko, &As[SBUF][w][0]);                          \
            gload_lds16(gb + ko, &Bs[SBUF][w][0]);                          \
        }                                                                   \
        _Pragma("unroll")                                                   \
        for (int i = 0; i < 2; ++i)                                         \
            _Pragma("unroll")                                               \
            for (int j = 0; j < 4; ++j)                                     \
                acc[i][j] = __builtin_amdgcn_mfma_f32_16x16x32_f16(         \
                    af[i], bf[j], acc[i][j], 0, 0, 0);                      \
        if ((TAILWAIT) == 2)                                                \
            asm volatile("s_waitcnt vmcnt(2)" ::: "memory");                \
        else if ((TAILWAIT) == 0)                                           \
            asm volatile("s_waitcnt vmcnt(0)" ::: "memory");                \
        if ((TAILWAIT) >= 0) __builtin_amdgcn_s_barrier();                  \
    }

__global__ __launch_bounds__(512) void gemm_qkv(const _Float16* __restrict__ xh, QkvP p)
{
    const int z = blockIdx.z;
    const _Float16* __restrict__ Wt   = p.Wt[z];
    const float* __restrict__    bias = p.bias[z];

    const int tid  = threadIdx.x;
    const int lane = tid & 63;
    const int w    = tid >> 6;        // 8 waves
    const int wr   = w >> 1, wc = w & 1;   // 4M x 2N wave grid
    const int quad = lane >> 4;
    const int l15  = lane & 15;
    const int bm   = blockIdx.x * 128;
    const int bn   = blockIdx.y * 128;

    __shared__ __align__(16) _Float16 As[3][8][512];
    __shared__ __align__(16) _Float16 Bs[3][8][512];

    const _Float16* ga = xh + (size_t)((bm >> 4) + w) * 16384 + lane * 8;
    const _Float16* gb = Wt + (size_t)((bn >> 4) + w) * 16384 + lane * 8;

    floatx4 acc[2][4];
#pragma unroll
    for (int i = 0; i < 2; ++i)
#pragma unroll
        for (int j = 0; j < 4; ++j)
            acc[i][j] = (floatx4){0.f, 0.f, 0.f, 0.f};

    gload_lds16(ga, &As[0][w][0]);
    gload_lds16(gb, &Bs[0][w][0]);
    gload_lds16(ga + 512, &As[1][w][0]);
    gload_lds16(gb + 512, &Bs[1][w][0]);
    asm volatile("s_waitcnt vmcnt(2)" ::: "memory");  // tile 0 landed
    __builtin_amdgcn_s_barrier();

    for (int tt = 0; tt < 30; tt += 3) {
        QKV_STEP(0, 2, tt + 2, true, 2);
        QKV_STEP(1, 0, tt + 3, true, 2);
        QKV_STEP(2, 1, tt + 4, true, 2);
    }
    QKV_STEP(0, 0, 0, false, 0);   // t=30: drain tile 31
    QKV_STEP(1, 0, 0, false, -1);  // t=31: no wait, no barrier

    if (z == 2) {
#pragma unroll
        for (int j = 0; j < 4; ++j) {
            const int col = bn + wc * 64 + j * 16 + l15;
            const int h  = col >> 6;
            const float bj = bias[col];
#pragma unroll
            for (int i = 0; i < 2; ++i) {
                const int t0 = bm + wr * 32 + i * 16 + quad * 4;
                const int bh = (t0 >> 10) * 16 + h;
                const int tm = t0 & 1023;
                half4 pk;
#pragma unroll
                for (int r = 0; r < 4; ++r) pk[r] = (_Float16)(acc[i][j][r] + bj);
                *(half4*)(p.vt + (size_t)bh * 65536 + (size_t)j * 16384
                          + (tm >> 3) * 128 + l15 * 8 + (tm & 7)) = pk;
            }
        }
    } else {
        _Float16* outp = (z == 0) ? p.qb : p.kb;
#pragma unroll
        for (int j = 0; j < 4; ++j) {
            const int col = bn + wc * 64 + j * 16 + l15;
            const int h  = col >> 6;
            const int dd = col & 63;
            const float bj = bias[col];
            const int doff = (dd >> 3) * 128 + (dd & 7);
#pragma unroll
            for (int i = 0; i < 2; ++i) {
#pragma unroll
                for (int r = 0; r < 4; ++r) {
                    const int tg = bm + wr * 32 + i * 16 + quad * 4 + r;
                    const int bh = (tg >> 10) * 16 + h;
                    const int tm = tg & 1023;
                    outp[(size_t)bh * 65536 + (tm >> 4) * 1024 + doff + (tm & 15) * 8] =
                        (_Float16)(acc[i][j][r] + bj);
                }
            }
        }
    }
}

// ---------------------------------------------------------------------------
// attn_mfma: ROUND-10 — T14 ping-pong KEPT, but the vmcnt-queue poison is
// removed: r9's per-iter GLOBAL pad loads (kk4) sat NEWEST in the vmcnt
// queue, so making them visible before softmax forced vmcnt(0), draining
// the entire K/V prefetch every iter (counters: VALUBusy 33 / Mfma 14.5 /
// HBM 7% -> still wait-bound). Fix: pad row staged to LDS ONCE (4 KB, one
// __syncthreads before the loop — r8 validated the mechanic); kk4 now reads
// LDS (lgkmcnt path). Loop body VMEM = ONLY the 16 t+1 prefetch loads ->
// prefetch genuinely rides under compute. LDS 20 KB, barrier-free loop.
// ---------------------------------------------------------------------------
#define ATTN_TILE(AKC, BVC, AKN, BVN, KTC, KTN, DOLOAD)                     \
    {                                                                       \
        if (DOLOAD) {                                                       \
            _Pragma("unroll")                                               \
            for (int ks = 0; ks < 2; ++ks) {                                \
                _Pragma("unroll")                                           \
                for (int mk = 0; mk < 4; ++mk)                              \
                    AKN[ks][mk] = *(const half8*)(kf                        \
                        + (size_t)(((KTN) >> 4) + mk) * 1024                \
                        + ks * 512 + lane * 8);                             \
                _Pragma("unroll")                                           \
                for (int dj = 0; dj < 4; ++dj)                              \
                    BVN[ks][dj] = *(const half8*)(vf + (size_t)dj * 16384   \
                        + ((KTN) >> 3) * 128 + ks * 512 + lane * 8);        \
            }                                                               \
        }                                                                   \
        float4 kk4[4];                                                      \
        _Pragma("unroll")                                                   \
        for (int mk = 0; mk < 4; ++mk)                                      \
            kk4[mk] = *(const float4*)&Pad[(KTC) + mk * 16 + quad * 4];     \
        floatx4 ST[4][2];                                                   \
        _Pragma("unroll")                                                   \
        for (int mk = 0; mk < 4; ++mk)                                      \
            _Pragma("unroll")                                               \
            for (int nq = 0; nq < 2; ++nq)                                  \
                ST[mk][nq] = (floatx4){0.f, 0.f, 0.f, 0.f};                 \
        _Pragma("unroll")                                                   \
        for (int ks = 0; ks < 2; ++ks)                                      \
            _Pragma("unroll")                                               \
            for (int mk = 0; mk < 4; ++mk)                                  \
                _Pragma("unroll")                                           \
                for (int nq = 0; nq < 2; ++nq)                              \
                    ST[mk][nq] = __builtin_amdgcn_mfma_f32_16x16x32_f16(    \
                        AKC[ks][mk], bq[ks][nq], ST[mk][nq], 0, 0, 0);      \
        _Pragma("unroll")                                                   \
        for (int mk = 0; mk < 4; ++mk) {                                    \
            const float kkr[4] = {1.0f - kk4[mk].x, 1.0f - kk4[mk].y,       \
                                  1.0f - kk4[mk].z, 1.0f - kk4[mk].w};      \
            _Pragma("unroll")                                               \
            for (int nq = 0; nq < 2; ++nq) {                                \
                half4 pk;                                                   \
                _Pragma("unroll")                                           \
                for (int r = 0; r < 4; ++r) {                               \
                    const float e = __builtin_amdgcn_exp2f(ST[mk][nq][r] * SC); \
                    const float pv = (kq[nq] == 0.0f) ? 1.0f : kkr[r] * e;  \
                    pk[r] = (_Float16)pv;                                   \
                }                                                           \
                *(half4*)&Ps[w][((mk * 2 + (quad >> 1)) * 32 + nq * 16 + l15) * 8 \
                               + (quad & 1) * 4] = pk;                      \
            }                                                               \
        }                                                                   \
        _Pragma("unroll")                                                   \
        for (int ks = 0; ks < 2; ++ks) {                                    \
            half8 ap[2];                                                    \
            _Pragma("unroll")                                               \
            for (int mi = 0; mi < 2; ++mi)                                  \
                ap[mi] = *(const half8*)&Ps[w][((ks * 4 + quad) * 32 + mi * 16 + l15) * 8]; \
            _Pragma("unroll")                                               \
            for (int mi = 0; mi < 2; ++mi) {                                \
                _Pragma("unroll")                                           \
                for (int dj = 0; dj < 4; ++dj)                              \
                    O[mi][dj] = __builtin_amdgcn_mfma_f32_16x16x32_f16(     \
                        ap[mi], BVC[ks][dj], O[mi][dj], 0, 0, 0);           \
                l_acc[mi] = __builtin_amdgcn_mfma_f32_16x16x32_f16(         \
                    ap[mi], ones, l_acc[mi], 0, 0, 0);                      \
            }                                                               \
        }                                                                   \
    }

__global__ __launch_bounds__(256) void attn_mfma(
    const _Float16* __restrict__ qb, const _Float16* __restrict__ kb,
    const _Float16* __restrict__ vt, const float* __restrict__ padj,
    _Float16* __restrict__ yh)
{
    __shared__ __align__(16) _Float16 Ps[4][2048];  // 16 KB wave-private P
    __shared__ __align__(16) float    Pad[1024];    //  4 KB pad row (LDS)

    const int tid  = threadIdx.x;
    const int lane = tid & 63;
    const int w    = tid >> 6;
    const int quad = lane >> 4;
    const int l15  = lane & 15;
    const int bh   = blockIdx.x;
    const int q0   = blockIdx.y * 128;
    const int b    = bh >> 4;
    const int h    = bh & 15;

    const _Float16* qf = qb + (size_t)bh * 65536;
    const _Float16* kf = kb + (size_t)bh * 65536;
    const _Float16* vf = vt + (size_t)bh * 65536;
    const float*    pk_row = padj + b * Tt;

    // pad row -> LDS once (256 threads x float4 = 1024 floats)
    *(float4*)&Pad[tid * 4] = *(const float4*)(pk_row + tid * 4);

    // Q frags: register-resident for entire K-loop (B-operand of S^T)
    half8 bq[2][2];
#pragma unroll
    for (int ks = 0; ks < 2; ++ks)
#pragma unroll
        for (int nq = 0; nq < 2; ++nq)
            bq[ks][nq] = *(const half8*)(qf + (size_t)((q0 >> 4) + w * 2 + nq) * 1024
                                         + ks * 512 + lane * 8);
    float kq[2];
#pragma unroll
    for (int nq = 0; nq < 2; ++nq)
        kq[nq] = 1.0f - pk_row[q0 + w * 32 + nq * 16 + l15];

    floatx4 O[2][4];
    floatx4 l_acc[2];
#pragma unroll
    for (int mi = 0; mi < 2; ++mi) {
#pragma unroll
        for (int dj = 0; dj < 4; ++dj) O[mi][dj] = (floatx4){0.f, 0.f, 0.f, 0.f};
        l_acc[mi] = (floatx4){0.f, 0.f, 0.f, 0.f};
    }
    half8 ones;
#pragma unroll
    for (int j = 0; j < 8; ++j) ones[j] = (_Float16)1.0f;

    constexpr float SC = 0.18033688011112042f;  // 0.125 * log2(e)

    __syncthreads();  // Pad visible (one-time)

    // T14 prologue: tile 0 -> register set 0
    half8 ak0[2][4], bv0[2][4], ak1[2][4], bv1[2][4];
#pragma unroll
    for (int ks = 0; ks < 2; ++ks) {
#pragma unroll
        for (int mk = 0; mk < 4; ++mk)
            ak0[ks][mk] = *(const half8*)(kf + (size_t)mk * 1024 + ks * 512 + lane * 8);
#pragma unroll
        for (int dj = 0; dj < 4; ++dj)
            bv0[ks][dj] = *(const half8*)(vf + (size_t)dj * 16384 + ks * 512 + lane * 8);
    }

    // 16 K/V tiles, 2x-unrolled ping-pong: load(t+1) issued before compute(t)
    for (int tt = 0; tt < 896; tt += 128) {
        ATTN_TILE(ak0, bv0, ak1, bv1, tt, tt + 64, true);
        ATTN_TILE(ak1, bv1, ak0, bv0, tt + 64, tt + 128, true);
    }
    ATTN_TILE(ak0, bv0, ak1, bv1, 896, 960, true);
    ATTN_TILE(ak1, bv1, ak0, bv0, 960, 0, false);

    // epilogue: normalize, write yh frag-swizzled (for LDS-free proj)
#pragma unroll
    for (int mi = 0; mi < 2; ++mi) {
#pragma unroll
        for (int r = 0; r < 4; ++r) {
            const int rowl  = w * 32 + mi * 16 + quad * 4 + r;
            const int token = b * Tt + q0 + rowl;
            const float inv = 1.0f / l_acc[mi][r];
            const size_t tb = (size_t)(token >> 4) * 16384 + (token & 15) * 8;
#pragma unroll
            for (int dj = 0; dj < 4; ++dj) {
                const int col = h * 64 + dj * 16 + l15;
                yh[tb + (col >> 3) * 128 + (col & 7)] = (_Float16)(O[mi][dj][r] * inv);
            }
        }
    }
}

// ---------------------------------------------------------------------------
// gemm_proj: ROUND-7 8-wave counted-vmcnt 5-buffer pipeline. UNCHANGED.
// ---------------------------------------------------------------------------
#define PROJ_STEP(CUR, SBUF, TS, DOSTAGE, TAILWAIT)                         \
    {                                                                       \
        half8 af[2], bf[4];                                                 \
        _Pragma("unroll")                                                   \
        for (int i = 0; i < 2; ++i)                                         \
            af[i] = *(const half8*)&As[CUR][wr * 2 + i][lane * 8];          \
        _Pragma("unroll")                                                   \
        for (int j = 0; j < 4; ++j)                                         \
            bf[j] = *(const half8*)&Bs[CUR][wc * 4 + j][lane * 8];          \
        if (DOSTAGE) {                                                      \
            const size_t ko = (size_t)(TS) * 512;                           \
            gload_lds16(ga + ko, &As[SBUF][w][0]);                          \
            gload_lds16(gb + ko, &Bs[SBUF][w][0]);                          \
        }                                                                   \
        _Pragma("unroll")                                                   \
        for (int i = 0; i < 2; ++i)                                         \
            _Pragma("unroll")                                               \
            for (int j = 0; j < 4; ++j)                                     \
                acc[i][j] = __builtin_amdgcn_mfma_f32_16x16x32_f16(         \
                    af[i], bf[j], acc[i][j], 0, 0, 0);                      \
        if ((TAILWAIT) == 6)                                                \
            asm volatile("s_waitcnt vmcnt(6)" ::: "memory");                \
        else if ((TAILWAIT) == 4)                                           \
            asm volatile("s_waitcnt vmcnt(4)" ::: "memory");                \
        else if ((TAILWAIT) == 2)                                           \
            asm volatile("s_waitcnt vmcnt(2)" ::: "memory");                \
        else if ((TAILWAIT) == 0)                                           \
            asm volatile("s_waitcnt vmcnt(0)" ::: "memory");                \
        if ((TAILWAIT) >= 0) __builtin_amdgcn_s_barrier();                  \
    }

__global__ __launch_bounds__(512) void gemm_proj(const _Float16* __restrict__ Ay,
                                                 const _Float16* __restrict__ Bt,
                                                 const float* __restrict__ bias,
                                                 float* __restrict__ out)
{
    const int tid  = threadIdx.x;
    const int lane = tid & 63;
    const int w    = tid >> 6;             // 8 waves
    const int wr   = w >> 1, wc = w & 1;   // 4M x 2N wave grid
    const int quad = lane >> 4;
    const int l15  = lane & 15;
    const int bm   = blockIdx.x * 128;
    const int bn   = blockIdx.y * 128;

    __shared__ __align__(16) _Float16 As[5][8][512];
    __shared__ __align__(16) _Float16 Bs[5][8][512];

    const _Float16* ga = Ay + (size_t)((bm >> 4) + w) * 16384 + lane * 8;
    const _Float16* gb = Bt + (size_t)((bn >> 4) + w) * 16384 + lane * 8;

    floatx4 acc[2][4];
#pragma unroll
    for (int i = 0; i < 2; ++i)
#pragma unroll
        for (int j = 0; j < 4; ++j)
            acc[i][j] = (floatx4){0.f, 0.f, 0.f, 0.f};

#pragma unroll
    for (int tb = 0; tb < 4; ++tb) {
        gload_lds16(ga + (size_t)tb * 512, &As[tb][w][0]);
        gload_lds16(gb + (size_t)tb * 512, &Bs[tb][w][0]);
    }
    asm volatile("s_waitcnt vmcnt(6)" ::: "memory");  // tile 0 landed
    __builtin_amdgcn_s_barrier();

    for (int tt = 0; tt < 25; tt += 5) {
        PROJ_STEP(0, 4, tt + 4, true, 6);
        PROJ_STEP(1, 0, tt + 5, true, 6);
        PROJ_STEP(2, 1, tt + 6, true, 6);
        PROJ_STEP(3, 2, tt + 7, true, 6);
        PROJ_STEP(4, 3, tt + 8, true, 6);
    }
    PROJ_STEP(0, 4, 29, true, 6);   // t=25
    PROJ_STEP(1, 0, 30, true, 6);   // t=26
    PROJ_STEP(2, 1, 31, true, 6);   // t=27
    PROJ_STEP(3, 0, 0, false, 4);   // t=28
    PROJ_STEP(4, 0, 0, false, 2);   // t=29
    PROJ_STEP(0, 0, 0, false, 0);   // t=30
    PROJ_STEP(1, 0, 0, false, -1);  // t=31

#pragma unroll
    for (int j = 0; j < 4; ++j) {
        const int col = bn + wc * 64 + j * 16 + l15;
        const float bj = bias[col];
#pragma unroll
        for (int i = 0; i < 2; ++i) {
            const int row = bm + wr * 32 + i * 16 + quad * 4;
            float* o = out + (size_t)row * 1024 + col;
#pragma unroll
            for (int r = 0; r < 4; ++r)
                o[(size_t)r * 1024] = acc[i][j][r] + bj;
        }
    }
}

// ---------------------------------------------------------------------------
extern "C" void kernel_launch(void* const* d_in, const int* in_sizes, int n_in,
                              void* d_out, int out_size, void* d_ws, size_t ws_size,
                              hipStream_t stream)
{
    const float* x    = (const float*)d_in[0];
    const float* padj = (const float*)d_in[1];
    const float* Wq   = (const float*)d_in[2];
    const float* bq   = (const float*)d_in[3];
    const float* Wk   = (const float*)d_in[4];
    const float* bk   = (const float*)d_in[5];
    const float* Wv   = (const float*)d_in[6];
    const float* bv   = (const float*)d_in[7];
    const float* Wp   = (const float*)d_in[8];
    const float* bp   = (const float*)d_in[9];
    float* out = (float*)d_out;

    const size_t MB = 1024 * 1024;
    char* ws = (char*)d_ws;
    _Float16* xh  = (_Float16*)(ws);            //  8 MB (frag-swizzled)
    _Float16* Wt0 = (_Float16*)(ws +  8 * MB);  //  2 MB
    _Float16* Wt1 = (_Float16*)(ws + 10 * MB);  //  2 MB
    _Float16* Wt2 = (_Float16*)(ws + 12 * MB);  //  2 MB
    _Float16* Wtp = (_Float16*)(ws + 14 * MB);  //  2 MB
    _Float16* qb  = (_Float16*)(ws + 16 * MB);  //  8 MB (per-bh frag)
    _Float16* kb  = (_Float16*)(ws + 24 * MB);  //  8 MB (per-bh frag)
    _Float16* vtb = (_Float16*)(ws + 32 * MB);  //  8 MB (per-bh frag)
    _Float16* yh  = (_Float16*)(ws + 40 * MB);  //  8 MB (frag-swizzled) -> 48 MB

    PrepP pp;
    pp.x = x; pp.xh = xh;
    pp.W[0] = Wq; pp.W[1] = Wk; pp.W[2] = Wv; pp.W[3] = Wp;
    pp.out[0] = Wt0; pp.out[1] = Wt1; pp.out[2] = Wt2; pp.out[3] = Wtp;
    prep_all<<<1280, 256, 0, stream>>>(pp);

    QkvP qp;
    qp.Wt[0] = Wt0; qp.Wt[1] = Wt1; qp.Wt[2] = Wt2;
    qp.bias[0] = bq; qp.bias[1] = bk; qp.bias[2] = bv;
    qp.qb = qb; qp.kb = kb; qp.vt = vtb;
    gemm_qkv<<<dim3(32, 8, 3), 512, 0, stream>>>(xh, qp);

    attn_mfma<<<dim3(64, 8), 256, 0, stream>>>(qb, kb, vtb, padj, yh);

    gemm_proj<<<dim3(32, 8), 512, 0, stream>>>(yh, Wtp, bp, out);
}